// Round 2
// baseline (45958.469 us; speedup 1.0000x reference)
//
#include <hip/hip_runtime.h>
#include <hip/hip_fp16.h>

#define HID   512
#define EMB   256
#define VOCAB 64
#define NL    2
#define BS    64
#define SLEN  128
#define LLEN  1024
#define G4    2048
#define NCH   4
#define NB    256      // persistent grid: one block per CU

// ---------------------------------------------------------------------------
// shared-memory union for the persistent kernel's phases
struct SMemCell { float As[64 * 130]; float red[4][8][66]; };
struct SMemLin  { float As[64 * 130]; float red[4][4][66]; };
struct SMemAttn { float u_s[HID]; float w_s[32]; float accs[16][34]; float msh[4];
                  unsigned enc[8352]; };
struct SMemLog  { float red[16][17]; };
union SMem { SMemCell cell; SMemLin lin; SMemAttn attn; SMemLog log; };

// ---------------------------------------------------------------------------
// device-scope grid barrier (monotonic counter, zeroed by memset each launch)
__device__ __forceinline__ void gridbar(unsigned* bar, unsigned expect)
{
    __syncthreads();
    if (threadIdx.x == 0) {
        __hip_atomic_fetch_add(bar, 1u, __ATOMIC_RELEASE, __HIP_MEMORY_SCOPE_AGENT);
        while (__hip_atomic_load(bar, __ATOMIC_ACQUIRE, __HIP_MEMORY_SCOPE_AGENT) < expect)
            __builtin_amdgcn_s_sleep(1);
    }
    __syncthreads();
}

// ---------------------------------------------------------------------------
// one-time kernels
__global__ __launch_bounds__(256)
void k_embed(const int* __restrict__ y, const float* __restrict__ emb,
             float* __restrict__ xemb)
{
    int i = blockIdx.x * 256 + threadIdx.x;
    int ts = i >> 14;
    int r  = i & 16383;
    int b  = r >> 8;
    int e  = r & 255;
    int yv = y[b * SLEN + ts];
    xemb[i] = emb[yv * EMB + e];
}

__global__ __launch_bounds__(256)
void k_cast(const float* __restrict__ src, __half* __restrict__ dst, int n4)
{
    int i = blockIdx.x * 256 + threadIdx.x;
    int stride = gridDim.x * 256;
    for (; i < n4; i += stride) {
        float4 v = reinterpret_cast<const float4*>(src)[i];
        __half2 lo = __floats2half2_rn(v.x, v.y);
        __half2 hi = __floats2half2_rn(v.z, v.w);
        reinterpret_cast<__half2*>(dst)[2 * i]     = lo;
        reinterpret_cast<__half2*>(dst)[2 * i + 1] = hi;
    }
}

__global__ __launch_bounds__(256)
void k_pmat(const float* __restrict__ Whw, const float* __restrict__ Wsw,
            const float* __restrict__ Wsb, float* __restrict__ P,
            float* __restrict__ p0)
{
    const int i = blockIdx.x;
    const int t = threadIdx.x;
    float a0 = 0.f, a1 = 0.f, ap = 0.f;
    for (int h = 0; h < HID; ++h) {
        float whi = Whw[h * HID + i];
        a0 += whi * Wsw[h * HID + t];
        a1 += whi * Wsw[h * HID + t + 256];
        ap += whi * Wsb[h];
    }
    P[i * HID + t]       = a0;
    P[i * HID + t + 256] = a1;
    if (t == 0) p0[i] = ap;
}

// ---------------------------------------------------------------------------
// phase: fused LSTM cell (same math as R1 k_cell)
__device__ __forceinline__ void phase_cell(SMem& sm, int bid,
    const float* __restrict__ A0, int K0,
    const float* __restrict__ A1, int K1,
    const float* __restrict__ A2,
    const float* __restrict__ Wih, int ldWih,
    const float* __restrict__ Whh,
    const float* __restrict__ bih, const float* __restrict__ bhh,
    float* __restrict__ c_io, float* __restrict__ h_out)
{
    const int t    = threadIdx.x;
    const int wv   = __builtin_amdgcn_readfirstlane(t >> 6);
    const int lane = t & 63;
    const int h0g  = bid * 2;

    float acc[2][4];
#pragma unroll
    for (int hl = 0; hl < 2; ++hl)
#pragma unroll
        for (int g = 0; g < 4; ++g) acc[hl][g] = 0.f;

    for (int ph = 0; ph < 3; ++ph) {
        const float* A; int K; const float* W; int ldW; int co;
        if (ph == 0)      { A = A0; K = K0;  W = Wih; ldW = ldWih; co = 0;  }
        else if (ph == 1) { A = A1; K = K1;  W = Wih; ldW = ldWih; co = K0; }
        else              { A = A2; K = HID; W = Whh; ldW = HID;   co = 0;  }
        if (K == 0) continue;
        for (int k0 = 0; k0 < K; k0 += 128) {
            __syncthreads();
#pragma unroll
            for (int p = 0; p < 8; ++p) {
                int f = p * 256 + t;
                int b = f >> 5;
                int q = f & 31;
                float4 d = *reinterpret_cast<const float4*>(A + (size_t)b * K + k0 + q * 4);
                float* dst = &sm.cell.As[b * 130 + q * 4];
                dst[0] = d.x; dst[1] = d.y; dst[2] = d.z; dst[3] = d.w;
            }
            __syncthreads();
            const int kw = wv * 32;
#pragma unroll
            for (int kk = 0; kk < 32; kk += 2) {
                float2 a = *reinterpret_cast<const float2*>(&sm.cell.As[lane * 130 + kw + kk]);
#pragma unroll
                for (int hl = 0; hl < 2; ++hl)
#pragma unroll
                    for (int g = 0; g < 4; ++g) {
                        const float* wp = W + (size_t)(g * HID + h0g + hl) * ldW + co + k0 + kw + kk;
                        acc[hl][g] += a.x * wp[0] + a.y * wp[1];
                    }
            }
        }
    }
    __syncthreads();
#pragma unroll
    for (int hl = 0; hl < 2; ++hl)
#pragma unroll
        for (int g = 0; g < 4; ++g)
            sm.cell.red[wv][hl * 4 + g][lane] = acc[hl][g];
    __syncthreads();
    if (t < 128) {
        const int b  = t & 63;
        const int hl = t >> 6;
        float gs[4];
#pragma unroll
        for (int g = 0; g < 4; ++g) {
            const int row = g * HID + h0g + hl;
            gs[g] = sm.cell.red[0][hl * 4 + g][b] + sm.cell.red[1][hl * 4 + g][b]
                  + sm.cell.red[2][hl * 4 + g][b] + sm.cell.red[3][hl * 4 + g][b]
                  + bih[row] + bhh[row];
        }
        const float ig = 1.f / (1.f + __expf(-gs[0]));
        const float fg = 1.f / (1.f + __expf(-gs[1]));
        const float gg = tanhf(gs[2]);
        const float og = 1.f / (1.f + __expf(-gs[3]));
        const int idx = b * HID + h0g + hl;
        const float c2 = fg * c_io[idx] + ig * gg;
        c_io[idx]  = c2;
        h_out[idx] = og * tanhf(c2);
    }
}

// ---------------------------------------------------------------------------
// phase: generic 2-rows-per-block linear over K=512
__device__ __forceinline__ void phase_lin(SMem& sm, int bid,
    const float* __restrict__ A, const float* __restrict__ W, int ldW,
    const float* __restrict__ bias, const float* __restrict__ addin,
    float* __restrict__ outp, int doRelu)
{
    const int t    = threadIdx.x;
    const int wv   = __builtin_amdgcn_readfirstlane(t >> 6);
    const int lane = t & 63;
    const int i0   = bid * 2;
    float acc[2] = {0.f, 0.f};

    for (int k0 = 0; k0 < HID; k0 += 128) {
        __syncthreads();
#pragma unroll
        for (int p = 0; p < 8; ++p) {
            int f = p * 256 + t;
            int b = f >> 5;
            int q = f & 31;
            float4 d = *reinterpret_cast<const float4*>(A + (size_t)b * HID + k0 + q * 4);
            float* dst = &sm.lin.As[b * 130 + q * 4];
            dst[0] = d.x; dst[1] = d.y; dst[2] = d.z; dst[3] = d.w;
        }
        __syncthreads();
        const int kw = wv * 32;
#pragma unroll
        for (int kk = 0; kk < 32; kk += 2) {
            float2 a = *reinterpret_cast<const float2*>(&sm.lin.As[lane * 130 + kw + kk]);
#pragma unroll
            for (int r = 0; r < 2; ++r) {
                const float* wp = W + (size_t)(i0 + r) * ldW + k0 + kw + kk;
                acc[r] += a.x * wp[0] + a.y * wp[1];
            }
        }
    }
    __syncthreads();
#pragma unroll
    for (int r = 0; r < 2; ++r) sm.lin.red[wv][r][lane] = acc[r];
    __syncthreads();
    if (t < 128) {
        const int b = t & 63;
        const int r = t >> 6;
        float s = sm.lin.red[0][r][b] + sm.lin.red[1][r][b]
                + sm.lin.red[2][r][b] + sm.lin.red[3][r][b];
        if (bias)  s += bias[i0 + r];
        if (addin) s += addin[b * HID + i0 + r];
        if (doRelu) s = fmaxf(s, 0.f);
        outp[b * HID + i0 + r] = s;
    }
}

// phase: dual linear — u = Pm*prev + p0  AND  hpart = W1a*prev + b1
__device__ __forceinline__ void phase_dual(SMem& sm, int bid,
    const float* __restrict__ A,
    const float* __restrict__ Wa, const float* __restrict__ ba, float* __restrict__ outa,
    const float* __restrict__ Wb, int ldb, const float* __restrict__ bb, float* __restrict__ outb)
{
    const int t    = threadIdx.x;
    const int wv   = __builtin_amdgcn_readfirstlane(t >> 6);
    const int lane = t & 63;
    const int i0   = bid * 2;
    float acc[4] = {0.f, 0.f, 0.f, 0.f};

    for (int k0 = 0; k0 < HID; k0 += 128) {
        __syncthreads();
#pragma unroll
        for (int p = 0; p < 8; ++p) {
            int f = p * 256 + t;
            int b = f >> 5;
            int q = f & 31;
            float4 d = *reinterpret_cast<const float4*>(A + (size_t)b * HID + k0 + q * 4);
            float* dst = &sm.lin.As[b * 130 + q * 4];
            dst[0] = d.x; dst[1] = d.y; dst[2] = d.z; dst[3] = d.w;
        }
        __syncthreads();
        const int kw = wv * 32;
#pragma unroll
        for (int kk = 0; kk < 32; kk += 2) {
            float2 a = *reinterpret_cast<const float2*>(&sm.lin.As[lane * 130 + kw + kk]);
#pragma unroll
            for (int r = 0; r < 2; ++r) {
                const float* wp = Wa + (size_t)(i0 + r) * HID + k0 + kw + kk;
                acc[r] += a.x * wp[0] + a.y * wp[1];
            }
#pragma unroll
            for (int r = 0; r < 2; ++r) {
                const float* wp = Wb + (size_t)(i0 + r) * ldb + k0 + kw + kk;
                acc[2 + r] += a.x * wp[0] + a.y * wp[1];
            }
        }
    }
    __syncthreads();
#pragma unroll
    for (int r = 0; r < 4; ++r) sm.lin.red[wv][r][lane] = acc[r];
    __syncthreads();
    {
        const int b = t & 63;
        const int r = t >> 6;
        float s = sm.lin.red[0][r][b] + sm.lin.red[1][r][b]
                + sm.lin.red[2][r][b] + sm.lin.red[3][r][b];
        if (r < 2) outa[b * HID + i0 + r]       = s + ba[i0 + r];
        else       outb[b * HID + i0 + (r - 2)] = s + bb[i0 + (r - 2)];
    }
}

// ---------------------------------------------------------------------------
// phase: attention partials (online softmax over 256 l per block)
template<int USE16>
__device__ __forceinline__ void phase_attn(SMem& sm, int bid,
    const float* __restrict__ uvec,
    const __half* __restrict__ enc16,
    const float* __restrict__ encf,
    float* __restrict__ pm, float* __restrict__ ps, float* __restrict__ pv)
{
    constexpr int ROWS = USE16 ? 32 : 16;
    constexpr int NBLK = 256 / ROWS;
    constexpr int SEGS = 256 / ROWS;
    constexpr int UPS  = 256 / SEGS;
    constexpr int LD16 = 261;
    constexpr int LDF  = 522;

    const int t  = threadIdx.x;
    const int b  = bid >> 2;
    const int ch = bid & 3;

    sm.attn.u_s[t]       = uvec[b * HID + t];
    sm.attn.u_s[t + 256] = uvec[b * HID + t + 256];
    if (t == 0) { sm.attn.msh[0] = -3.0e38f; sm.attn.msh[1] = 0.f; sm.attn.msh[2] = 0.f; }
    float vx = 0.f, vy = 0.f;
    __syncthreads();

    for (int blk = 0; blk < NBLK; ++blk) {
        const int l0 = ch * 256 + blk * ROWS;
        if constexpr (USE16) {
            const uint4* src = reinterpret_cast<const uint4*>(enc16 + ((size_t)b * LLEN + l0) * HID);
#pragma unroll
            for (int p = 0; p < ROWS * 64 / 256; ++p) {
                int f = p * 256 + t;
                int l = f >> 6, q = f & 63;
                uint4 d = src[l * 64 + q];
                unsigned* dst = &sm.attn.enc[l * LD16 + q * 4];
                dst[0] = d.x; dst[1] = d.y; dst[2] = d.z; dst[3] = d.w;
            }
        } else {
            const float4* src = reinterpret_cast<const float4*>(encf + ((size_t)b * LLEN + l0) * HID);
            float* es = reinterpret_cast<float*>(sm.attn.enc);
#pragma unroll
            for (int p = 0; p < ROWS * 128 / 256; ++p) {
                int f = p * 256 + t;
                int l = f >> 7, q = f & 127;
                float4 d = src[l * 128 + q];
                float* dst = &es[l * LDF + q * 4];
                dst[0] = d.x; dst[1] = d.y; dst[2] = d.z; dst[3] = d.w;
            }
        }
        __syncthreads();
        {   // scores
            const int l   = t % ROWS;
            const int seg = t / ROWS;
            float acc = 0.f;
            if constexpr (USE16) {
                const unsigned* er = &sm.attn.enc[l * LD16];
#pragma unroll
                for (int uu = 0; uu < UPS; ++uu) {
                    const int u = seg * UPS + uu;
                    float2 f2 = __half22float2(*reinterpret_cast<const __half2*>(&er[u]));
                    float2 uv = *reinterpret_cast<const float2*>(&sm.attn.u_s[2 * u]);
                    acc += uv.x * f2.x + uv.y * f2.y;
                }
            } else {
                const float* er = reinterpret_cast<const float*>(sm.attn.enc) + l * LDF;
#pragma unroll
                for (int uu = 0; uu < UPS; ++uu) {
                    const int u = seg * UPS + uu;
                    float2 f2 = *reinterpret_cast<const float2*>(&er[2 * u]);
                    float2 uv = *reinterpret_cast<const float2*>(&sm.attn.u_s[2 * u]);
                    acc += uv.x * f2.x + uv.y * f2.y;
                }
            }
            sm.attn.accs[seg][l] = acc;
        }
        __syncthreads();
        if (t < ROWS) {
            float e = 0.f;
#pragma unroll
            for (int s2 = 0; s2 < SEGS; ++s2) e += sm.attn.accs[s2][t];
            float bm = e;
#pragma unroll
            for (int off = ROWS / 2; off > 0; off >>= 1) bm = fmaxf(bm, __shfl_xor(bm, off));
            const float m_old = sm.attn.msh[0];
            const float m_new = fmaxf(m_old, bm);
            const float wl = __expf(e - m_new);
            float sw = wl;
#pragma unroll
            for (int off = ROWS / 2; off > 0; off >>= 1) sw += __shfl_xor(sw, off);
            sm.attn.w_s[t] = wl;
            if (t == 0) {
                const float sc = __expf(m_old - m_new);
                sm.attn.msh[2] = sc;
                sm.attn.msh[1] = sm.attn.msh[1] * sc + sw;
                sm.attn.msh[0] = m_new;
            }
        }
        __syncthreads();
        {   // weighted accumulate
            const float sc = sm.attn.msh[2];
            vx *= sc; vy *= sc;
            if constexpr (USE16) {
#pragma unroll
                for (int l = 0; l < ROWS; ++l) {
                    float wl = sm.attn.w_s[l];
                    float2 f2 = __half22float2(*reinterpret_cast<const __half2*>(&sm.attn.enc[l * LD16 + t]));
                    vx += wl * f2.x; vy += wl * f2.y;
                }
            } else {
                const float* ef = reinterpret_cast<const float*>(sm.attn.enc);
#pragma unroll
                for (int l = 0; l < ROWS; ++l) {
                    float wl = sm.attn.w_s[l];
                    float2 f2 = *reinterpret_cast<const float2*>(&ef[l * LDF + 2 * t]);
                    vx += wl * f2.x; vy += wl * f2.y;
                }
            }
        }
        __syncthreads();
    }
    const int pc = b * NCH + ch;
    if (t == 0) { pm[pc] = sm.attn.msh[0]; ps[pc] = sm.attn.msh[1]; }
    pv[(size_t)pc * HID + 2 * t]     = vx;
    pv[(size_t)pc * HID + 2 * t + 1] = vy;
}

// phase: combine chunk partials -> chat
__device__ __forceinline__ void phase_combine(int bid,
    const float* __restrict__ pm, const float* __restrict__ ps,
    const float* __restrict__ pv, float* __restrict__ chat)
{
    const int t = threadIdx.x;
    if (t < 128) {
        int i = bid * 128 + t;
        int b = i >> 9;
        int j = i & 511;
        float m0 = pm[b * 4], m1 = pm[b * 4 + 1], m2 = pm[b * 4 + 2], m3 = pm[b * 4 + 3];
        float M  = fmaxf(fmaxf(m0, m1), fmaxf(m2, m3));
        float e0 = __expf(m0 - M), e1 = __expf(m1 - M), e2 = __expf(m2 - M), e3 = __expf(m3 - M);
        float den = e0 * ps[b * 4] + e1 * ps[b * 4 + 1] + e2 * ps[b * 4 + 2] + e3 * ps[b * 4 + 3];
        float num = e0 * pv[(size_t)(b * 4 + 0) * HID + j] + e1 * pv[(size_t)(b * 4 + 1) * HID + j]
                  + e2 * pv[(size_t)(b * 4 + 2) * HID + j] + e3 * pv[(size_t)(b * 4 + 3) * HID + j];
        chat[i] = num / den;
    }
}

// phase: logits for one step (256 blocks = 64 b x 4 v-groups)
__device__ __forceinline__ void phase_logits(SMem& sm, int bid,
    const float* __restrict__ hid, const float* __restrict__ W2,
    const float* __restrict__ b2, float* __restrict__ out, int tstep)
{
    const int t  = threadIdx.x;
    const int b  = bid & 63;
    const int vg = bid >> 6;
    const int vp = t >> 4;
    const int kk = t & 15;
    const int v  = vg * 16 + vp;
    const float* w = W2 + (size_t)v * HID + kk * 32;
    const float* h = hid + (size_t)b * HID + kk * 32;
    float s = 0.f;
#pragma unroll
    for (int k = 0; k < 32; ++k) s += w[k] * h[k];
    sm.log.red[vp][kk] = s;
    __syncthreads();
    if (t < 16) {
        float acc = b2[vg * 16 + t];
#pragma unroll
        for (int k = 0; k < 16; ++k) acc += sm.log.red[t][k];
        out[((size_t)b * SLEN + tstep) * VOCAB + vg * 16 + t] = acc;
    }
}

// ---------------------------------------------------------------------------
// THE persistent kernel: entire 128-step loop, grid barriers between phases
template<int USE16>
__global__ __launch_bounds__(256)
void k_seq(const float* __restrict__ xemb, const __half* __restrict__ enc16,
           const float* __restrict__ encf,
           const float* __restrict__ aWih, const float* __restrict__ aWhh,
           const float* __restrict__ abih, const float* __restrict__ abhh,
           const float* __restrict__ rWih, const float* __restrict__ rWhh,
           const float* __restrict__ rbih, const float* __restrict__ rbhh,
           const float* __restrict__ Pm, const float* __restrict__ p0v,
           const float* __restrict__ Whw, const float* __restrict__ Whb,
           const float* __restrict__ W1, const float* __restrict__ b1,
           const float* __restrict__ W2, const float* __restrict__ b2,
           float* h0, float* c0, float* hs, float* cs,
           float* ctxb, float* ub, float* chat, float* hpart, float* hid,
           float* pm, float* ps, float* pv, float* out, unsigned* bar)
{
    __shared__ SMem sm;
    const int bid = blockIdx.x;
    unsigned expect = 0;

    for (int t = 0; t < SLEN; ++t) {
        const int par = t & 1;
        float* h0r = h0 + par * BS * HID;
        float* h0w = h0 + (par ^ 1) * BS * HID;
        float* hsr = hs + par * NL * BS * HID;
        float* hsw = hs + (par ^ 1) * NL * BS * HID;
        float* prev = hsw + BS * HID;

        // A: attention-input LSTM cell
        phase_cell(sm, bid, xemb + (size_t)t * BS * EMB, EMB, ctxb, HID, h0r,
                   aWih, EMB + HID, aWhh, abih, abhh, c0, h0w);
        gridbar(bar, expect += NB);
        // B: rnn layer 0
        phase_cell(sm, bid, h0w, HID, nullptr, 0, hsr,
                   rWih, HID, rWhh, rbih, rbhh, cs, hsw);
        gridbar(bar, expect += NB);
        // C: rnn layer 1
        phase_cell(sm, bid, hsw, HID, nullptr, 0, hsr + BS * HID,
                   rWih + (size_t)G4 * HID, HID, rWhh + (size_t)G4 * HID,
                   rbih + G4, rbhh + G4, cs + BS * HID, prev);
        gridbar(bar, expect += NB);
        // D: logits(t-1) + u = Pm*prev + p0 + hpart = W1a*prev + b1
        if (t > 0) phase_logits(sm, bid, hid, W2, b2, out, t - 1);
        __syncthreads();
        phase_dual(sm, bid, prev, Pm, p0v, ub, W1, 2 * HID, b1, hpart);
        gridbar(bar, expect += NB);
        // E: attention partials
        phase_attn<USE16>(sm, bid, ub, enc16, encf, pm, ps, pv);
        gridbar(bar, expect += NB);
        // F: combine -> chat
        phase_combine(bid, pm, ps, pv, chat);
        gridbar(bar, expect += NB);
        // G: ctx = Whw*chat + Whb
        phase_lin(sm, bid, chat, Whw, HID, Whb, nullptr, ctxb, 0);
        gridbar(bar, expect += NB);
        // H: hidden = relu(hpart + W1b*ctx)
        phase_lin(sm, bid, ctxb, W1 + HID, 2 * HID, nullptr, hpart, hid, 1);
        gridbar(bar, expect += NB);
    }
    phase_logits(sm, bid, hid, W2, b2, out, SLEN - 1);
}

// ---------------------------------------------------------------------------
extern "C" void kernel_launch(void* const* d_in, const int* in_sizes, int n_in,
                              void* d_out, int out_size, void* d_ws, size_t ws_size,
                              hipStream_t stream)
{
    const int*   y    = (const int*)  d_in[0];
    const float* enc  = (const float*)d_in[1];
    const float* emb  = (const float*)d_in[2];
    const float* aWih = (const float*)d_in[3];
    const float* aWhh = (const float*)d_in[4];
    const float* abih = (const float*)d_in[5];
    const float* abhh = (const float*)d_in[6];
    const float* rWih = (const float*)d_in[7];
    const float* rWhh = (const float*)d_in[8];
    const float* rbih = (const float*)d_in[9];
    const float* rbhh = (const float*)d_in[10];
    const float* Wsw  = (const float*)d_in[11];
    const float* Wsb  = (const float*)d_in[12];
    const float* Whw  = (const float*)d_in[13];
    const float* Whb  = (const float*)d_in[14];
    const float* W1   = (const float*)d_in[15];
    const float* b1   = (const float*)d_in[16];
    const float* W2   = (const float*)d_in[17];
    const float* b2   = (const float*)d_in[18];
    float* out = (float*)d_out;

    unsigned* bar = (unsigned*)d_ws;
    float* p = (float*)((char*)d_ws + 256);
    // zeroed-region (contiguous): h0(2), c0, hs(2), cs, ctxb
    float* h0   = p;  p += 2 * BS * HID;
    float* c0   = p;  p += BS * HID;
    float* hs   = p;  p += 2 * NL * BS * HID;
    float* cs   = p;  p += NL * BS * HID;
    float* ctxb = p;  p += BS * HID;
    // live buffers
    float* ub    = p;  p += BS * HID;
    float* chat  = p;  p += BS * HID;
    float* hpart = p;  p += BS * HID;
    float* hid   = p;  p += BS * HID;
    float* Pm    = p;  p += HID * HID;
    float* p0v   = p;  p += HID;
    float* pmb   = p;  p += BS * NCH;
    float* psb   = p;  p += BS * NCH;
    float* pvb   = p;  p += (size_t)BS * NCH * HID;
    float* xemb  = p;  p += (size_t)SLEN * BS * EMB;
    __half* enc16 = (__half*)p;
    size_t need = (size_t)((char*)p - (char*)d_ws) + sizeof(__half) * (size_t)BS * LLEN * HID;
    const bool use16 = (ws_size >= need);

    hipMemsetAsync(bar, 0, 256, stream);
    size_t zeroFloats = (size_t)(2 + 1 + 2 * NL + NL + 1) * BS * HID;
    hipMemsetAsync(h0, 0, zeroFloats * sizeof(float), stream);

    k_embed<<<(SLEN * BS * EMB) / 256, 256, 0, stream>>>(y, emb, xemb);
    if (use16) k_cast<<<4096, 256, 0, stream>>>(enc, enc16, (BS * LLEN * HID) / 4);
    k_pmat<<<HID, 256, 0, stream>>>(Whw, Wsw, Wsb, Pm, p0v);

    if (use16)
        k_seq<1><<<NB, 256, 0, stream>>>(xemb, enc16, nullptr,
            aWih, aWhh, abih, abhh, rWih, rWhh, rbih, rbhh,
            Pm, p0v, Whw, Whb, W1, b1, W2, b2,
            h0, c0, hs, cs, ctxb, ub, chat, hpart, hid,
            pmb, psb, pvb, out, bar);
    else
        k_seq<0><<<NB, 256, 0, stream>>>(xemb, nullptr, enc,
            aWih, aWhh, abih, abhh, rWih, rWhh, rbih, rbhh,
            Pm, p0v, Whw, Whb, W1, b1, W2, b2,
            h0, c0, hs, cs, ctxb, ub, chat, hpart, hid,
            pmb, psb, pvb, out, bar);
}

// Round 3
// 42272.610 us; speedup vs baseline: 1.0872x; 1.0872x over previous
//
#include <hip/hip_runtime.h>
#include <hip/hip_fp16.h>

#define HID   512
#define EMB   256
#define VOCAB 64
#define NL    2
#define BS    64
#define SLEN  128
#define LLEN  1024
#define G4    2048
#define NCH   4
#define NB    256
#define NT    512

// ---------------------------------------------------------------------------
struct SAttn {
    float u_s[512];
    float w_s[32];
    float msh[4];
    float accs[16][34];
    unsigned enc[32 * 261];   // 32 rows x 256 half2, stride 261 u32 (bank-spread)
};
struct SCell { float red[8][8][66]; };
struct SLog  { float red[16 * 33]; };
union SMem { SAttn attn; SCell cell; SLog log; };

// ---------------------------------------------------------------------------
// hierarchical grid barrier: 8 group counters (64B apart) + 1 top counter
__device__ __forceinline__ void gridbar(unsigned* bar, unsigned nb)
{
    __syncthreads();
    if (threadIdx.x == 0) {
        unsigned* grp = bar + (blockIdx.x & 7) * 16;
        unsigned old = __hip_atomic_fetch_add(grp, 1u, __ATOMIC_ACQ_REL,
                                              __HIP_MEMORY_SCOPE_AGENT);
        if (old == nb * 32u - 1u)
            __hip_atomic_fetch_add(bar + 128, 1u, __ATOMIC_ACQ_REL,
                                   __HIP_MEMORY_SCOPE_AGENT);
        while (__hip_atomic_load(bar + 128, __ATOMIC_ACQUIRE,
                                 __HIP_MEMORY_SCOPE_AGENT) < nb * 8u)
            __builtin_amdgcn_s_sleep(1);
    }
    __syncthreads();
}

// ---------------------------------------------------------------------------
// one-time kernels
__global__ __launch_bounds__(256)
void k_embed(const int* __restrict__ y, const float* __restrict__ emb,
             float* __restrict__ xemb)
{
    int i = blockIdx.x * 256 + threadIdx.x;
    int ts = i >> 14;
    int r  = i & 16383;
    int b  = r >> 8;
    int e  = r & 255;
    xemb[i] = emb[y[b * SLEN + ts] * EMB + e];
}

__global__ __launch_bounds__(256)
void k_cast(const float* __restrict__ src, __half* __restrict__ dst, int n4)
{
    int i = blockIdx.x * 256 + threadIdx.x;
    int stride = gridDim.x * 256;
    for (; i < n4; i += stride) {
        float4 v = reinterpret_cast<const float4*>(src)[i];
        reinterpret_cast<__half2*>(dst)[2 * i]     = __floats2half2_rn(v.x, v.y);
        reinterpret_cast<__half2*>(dst)[2 * i + 1] = __floats2half2_rn(v.z, v.w);
    }
}

__global__ __launch_bounds__(256)
void k_pmat(const float* __restrict__ Whw, const float* __restrict__ Wsw,
            const float* __restrict__ Wsb, float* __restrict__ P,
            float* __restrict__ p0)
{
    const int i = blockIdx.x;
    const int t = threadIdx.x;
    float a0 = 0.f, a1 = 0.f, ap = 0.f;
    for (int h = 0; h < HID; ++h) {
        float whi = Whw[h * HID + i];
        a0 += whi * Wsw[h * HID + t];
        a1 += whi * Wsw[h * HID + t + 256];
        ap += whi * Wsb[h];
    }
    P[i * HID + t]       = a0;
    P[i * HID + t + 256] = a1;
    if (t == 0) p0[i] = ap;
}

// ---------------------------------------------------------------------------
// k-segment accumulate for one LSTM cell: 8 gate-rows, direct loads
template<int KN>
__device__ __forceinline__ void seg_acc(float (&acc)[2][4],
    const float* __restrict__ ap, const float* __restrict__ wbase,
    int ldW, int h0g)
{
    const float* w[8];
#pragma unroll
    for (int r = 0; r < 8; ++r)
        w[r] = wbase + (size_t)((r & 3) * HID + h0g + (r >> 2)) * ldW;
#pragma unroll 4
    for (int k = 0; k < KN; ++k) {
        const float a = ap[k];
#pragma unroll
        for (int r = 0; r < 8; ++r)
            acc[r >> 2][r & 3] += a * w[r][k];
    }
}

// fused LSTM cell, 8 rows/block, direct activation loads (no LDS staging)
template<int KX, bool HASC>
__device__ __forceinline__ void phase_cell(SMem& sm, int h0g,
    const float* __restrict__ Ax,
    const float* __restrict__ Ac,
    const float* __restrict__ Ah,
    const float* __restrict__ Wih, int ldWih,
    const float* __restrict__ Whh,
    const float* __restrict__ bih, const float* __restrict__ bhh,
    float* __restrict__ c_io, float* __restrict__ h_out)
{
    const int t    = threadIdx.x;
    const int wv   = __builtin_amdgcn_readfirstlane(t >> 6);
    const int lane = t & 63;
    float acc[2][4] = {};

    {   // x-part through Wih cols [0, KX)
        constexpr int KN = KX / 8;
        const int kb = wv * KN;
        seg_acc<KN>(acc, Ax + (size_t)lane * KX + kb, Wih + kb, ldWih, h0g);
    }
    if constexpr (HASC) {   // ctx part through Wih cols [KX, KX+HID)
        const int kb = wv * 64;
        seg_acc<64>(acc, Ac + (size_t)lane * HID + kb, Wih + KX + kb, ldWih, h0g);
    }
    {   // h-part through Whh
        const int kb = wv * 64;
        seg_acc<64>(acc, Ah + (size_t)lane * HID + kb, Whh + kb, HID, h0g);
    }
    __syncthreads();
#pragma unroll
    for (int hl = 0; hl < 2; ++hl)
#pragma unroll
        for (int g = 0; g < 4; ++g)
            sm.cell.red[wv][hl * 4 + g][lane] = acc[hl][g];
    __syncthreads();
    if (t < 128) {
        const int b  = t & 63;
        const int hl = t >> 6;
        float gs[4];
#pragma unroll
        for (int g = 0; g < 4; ++g) {
            const int row = g * HID + h0g + hl;
            float s = bih[row] + bhh[row];
#pragma unroll
            for (int w = 0; w < 8; ++w) s += sm.cell.red[w][hl * 4 + g][b];
            gs[g] = s;
        }
        const float ig = 1.f / (1.f + __expf(-gs[0]));
        const float fg = 1.f / (1.f + __expf(-gs[1]));
        const float gg = tanhf(gs[2]);
        const float og = 1.f / (1.f + __expf(-gs[3]));
        const int idx = b * HID + h0g + hl;
        const float c2 = fg * c_io[idx] + ig * gg;
        c_io[idx]  = c2;
        h_out[idx] = og * tanhf(c2);
    }
}

// dual GEMV: ub = Pm@prev + p0  AND  hpart = W1a@prev + b1  (4 rows/block)
__device__ __forceinline__ void phase_dual(SMem& sm, int i0,
    const float* __restrict__ prev,
    const float* __restrict__ Pm, const float* __restrict__ p0v, float* __restrict__ ub,
    const float* __restrict__ W1, const float* __restrict__ b1, float* __restrict__ hpart)
{
    const int t    = threadIdx.x;
    const int wv   = __builtin_amdgcn_readfirstlane(t >> 6);
    const int lane = t & 63;
    const int kb   = wv * 64;
    const float* ap = prev + (size_t)lane * HID + kb;
    const float* q0 = Pm + (size_t)i0 * HID + kb;
    const float* q1 = q0 + HID;
    const float* q2 = W1 + (size_t)i0 * (2 * HID) + kb;
    const float* q3 = q2 + 2 * HID;
    float a0 = 0.f, a1 = 0.f, a2 = 0.f, a3 = 0.f;
#pragma unroll 4
    for (int k = 0; k < 64; ++k) {
        const float a = ap[k];
        a0 += a * q0[k]; a1 += a * q1[k]; a2 += a * q2[k]; a3 += a * q3[k];
    }
    __syncthreads();
    sm.cell.red[wv][0][lane] = a0;
    sm.cell.red[wv][1][lane] = a1;
    sm.cell.red[wv][2][lane] = a2;
    sm.cell.red[wv][3][lane] = a3;
    __syncthreads();
    if (t < 256) {
        const int b = t & 63;
        const int r = t >> 6;
        float s = 0.f;
#pragma unroll
        for (int w = 0; w < 8; ++w) s += sm.cell.red[w][r][b];
        if (r < 2) ub[b * HID + i0 + r]          = s + p0v[i0 + r];
        else       hpart[b * HID + i0 + (r - 2)] = s + b1[i0 + (r - 2)];
    }
}

// hid = relu(hpart + W1b@ctx)   (2 rows/block)
__device__ __forceinline__ void phase_H(SMem& sm, int i0,
    const float* __restrict__ ctxb, const float* __restrict__ W1,
    const float* __restrict__ hpart, float* __restrict__ hid)
{
    const int t    = threadIdx.x;
    const int wv   = __builtin_amdgcn_readfirstlane(t >> 6);
    const int lane = t & 63;
    const int kb   = wv * 64;
    const float* ap = ctxb + (size_t)lane * HID + kb;
    const float* w0 = W1 + (size_t)i0 * (2 * HID) + HID + kb;
    const float* w1 = w0 + 2 * HID;
    float a0 = 0.f, a1 = 0.f;
#pragma unroll 4
    for (int k = 0; k < 64; ++k) { const float a = ap[k]; a0 += a * w0[k]; a1 += a * w1[k]; }
    __syncthreads();
    sm.cell.red[wv][0][lane] = a0;
    sm.cell.red[wv][1][lane] = a1;
    __syncthreads();
    if (t < 128) {
        const int b = t & 63;
        const int r = t >> 6;
        float s = hpart[b * HID + i0 + r];
#pragma unroll
        for (int w = 0; w < 8; ++w) s += sm.cell.red[w][r][b];
        hid[b * HID + i0 + r] = fmaxf(s, 0.f);
    }
}

// ctx = Whw@chat + Whb   (2 rows/block)
__device__ __forceinline__ void phase_G(SMem& sm, int i0,
    const float* __restrict__ chat, const float* __restrict__ Whw,
    const float* __restrict__ Whb, float* __restrict__ ctxb)
{
    const int t    = threadIdx.x;
    const int wv   = __builtin_amdgcn_readfirstlane(t >> 6);
    const int lane = t & 63;
    const int kb   = wv * 64;
    const float* ap = chat + (size_t)lane * HID + kb;
    const float* w0 = Whw + (size_t)i0 * HID + kb;
    const float* w1 = w0 + HID;
    float a0 = 0.f, a1 = 0.f;
#pragma unroll 4
    for (int k = 0; k < 64; ++k) { const float a = ap[k]; a0 += a * w0[k]; a1 += a * w1[k]; }
    __syncthreads();
    sm.cell.red[wv][0][lane] = a0;
    sm.cell.red[wv][1][lane] = a1;
    __syncthreads();
    if (t < 128) {
        const int b = t & 63;
        const int r = t >> 6;
        float s = Whb[i0 + r];
#pragma unroll
        for (int w = 0; w < 8; ++w) s += sm.cell.red[w][r][b];
        ctxb[b * HID + i0 + r] = s;
    }
}

// combine chunk partials -> chat
__device__ __forceinline__ void phase_F(int bid,
    const float* __restrict__ pm, const float* __restrict__ ps,
    const float* __restrict__ pv, float* __restrict__ chat)
{
    const int t = threadIdx.x;
    if (t < 128) {
        const int i = bid * 128 + t;
        const int b = i >> 9;
        const int j = i & 511;
        float m0 = pm[b * 4], m1 = pm[b * 4 + 1], m2 = pm[b * 4 + 2], m3 = pm[b * 4 + 3];
        float M  = fmaxf(fmaxf(m0, m1), fmaxf(m2, m3));
        float e0 = __expf(m0 - M), e1 = __expf(m1 - M), e2 = __expf(m2 - M), e3 = __expf(m3 - M);
        float den = e0 * ps[b * 4] + e1 * ps[b * 4 + 1] + e2 * ps[b * 4 + 2] + e3 * ps[b * 4 + 3];
        float num = e0 * pv[(size_t)(b * 4 + 0) * HID + j] + e1 * pv[(size_t)(b * 4 + 1) * HID + j]
                  + e2 * pv[(size_t)(b * 4 + 2) * HID + j] + e3 * pv[(size_t)(b * 4 + 3) * HID + j];
        chat[i] = num / den;
    }
}

// logits for one step (block -> (b, v-group of 16))
__device__ __forceinline__ void phase_logits(SMem& sm, int bid,
    const float* __restrict__ hid, const float* __restrict__ W2,
    const float* __restrict__ b2, float* __restrict__ out, int tstep)
{
    const int t  = threadIdx.x;
    const int b  = bid & 63;
    const int vg = bid >> 6;
    const int vp = t >> 5;
    const int kk = t & 31;
    const float* w = W2 + (size_t)(vg * 16 + vp) * HID + kk * 16;
    const float* h = hid + (size_t)b * HID + kk * 16;
    float s = 0.f;
#pragma unroll
    for (int k = 0; k < 16; ++k) s += w[k] * h[k];
    __syncthreads();
    sm.log.red[vp * 33 + kk] = s;
    __syncthreads();
    if (t < 16) {
        float acc = b2[vg * 16 + t];
#pragma unroll
        for (int k = 0; k < 32; ++k) acc += sm.log.red[t * 33 + k];
        out[((size_t)b * SLEN + tstep) * VOCAB + vg * 16 + t] = acc;
    }
}

// attention partials, f16 LDS-staged with register prefetch
__device__ __forceinline__ void phase_attn16(SMem& sm, int bid,
    const float* __restrict__ uvec, const __half* __restrict__ enc16,
    float* __restrict__ pm, float* __restrict__ ps, float* __restrict__ pv)
{
    const int t    = threadIdx.x;
    const int b    = bid >> 2;
    const int ch   = bid & 3;
    const int half = t >> 8;
    const int col  = t & 255;
    const int le   = t & 31;
    const int seg  = t >> 5;
    const int sq   = t & 15;
    const int sl   = (t >> 4) & 31;

    sm.attn.u_s[t] = uvec[b * HID + t];
    if (t == 0) { sm.attn.msh[0] = -3.0e38f; sm.attn.msh[1] = 0.f; sm.attn.msh[2] = 0.f; }
    float vx = 0.f, vy = 0.f;

    const uint4* src = reinterpret_cast<const uint4*>(enc16 + ((size_t)b * LLEN + ch * 256) * HID);
    uint4 R[4];
#pragma unroll
    for (int p = 0; p < 4; ++p) R[p] = src[(size_t)sl * 64 + p * 16 + sq];
    __syncthreads();

    for (int blk = 0; blk < 8; ++blk) {
        {   // scalar u32 stores (bank-spread, 2-way max)
            unsigned* dst = &sm.attn.enc[sl * 261];
#pragma unroll
            for (int p = 0; p < 4; ++p) {
                const int c4 = (p * 16 + sq) * 4;
                dst[c4]     = R[p].x; dst[c4 + 1] = R[p].y;
                dst[c4 + 2] = R[p].z; dst[c4 + 3] = R[p].w;
            }
        }
        __syncthreads();
        if (blk < 7) {
#pragma unroll
            for (int p = 0; p < 4; ++p)
                R[p] = src[((size_t)(blk + 1) * 32 + sl) * 64 + p * 16 + sq];
        }
        {   // scores
            float eacc = 0.f;
            const unsigned* er = &sm.attn.enc[le * 261];
            const float* us = sm.attn.u_s;
#pragma unroll
            for (int uu = 0; uu < 16; ++uu) {
                const int u = seg * 16 + uu;
                float2 f2 = __half22float2(*reinterpret_cast<const __half2*>(&er[u]));
                eacc += us[2 * u] * f2.x + us[2 * u + 1] * f2.y;
            }
            sm.attn.accs[seg][le] = eacc;
        }
        __syncthreads();
        if (t < 32) {
            float e = 0.f;
#pragma unroll
            for (int s2 = 0; s2 < 16; ++s2) e += sm.attn.accs[s2][t];
            float bm = e;
#pragma unroll
            for (int off = 16; off > 0; off >>= 1) bm = fmaxf(bm, __shfl_xor(bm, off));
            const float m_old = sm.attn.msh[0];
            const float m_new = fmaxf(m_old, bm);
            const float wl = __expf(e - m_new);
            float sw = wl;
#pragma unroll
            for (int off = 16; off > 0; off >>= 1) sw += __shfl_xor(sw, off);
            sm.attn.w_s[t] = wl;
            if (t == 0) {
                const float sc = __expf(m_old - m_new);
                sm.attn.msh[2] = sc;
                sm.attn.msh[1] = sm.attn.msh[1] * sc + sw;
                sm.attn.msh[0] = m_new;
            }
        }
        __syncthreads();
        {   // weighted accumulate (16 rows per half)
            const float sc = sm.attn.msh[2];
            vx *= sc; vy *= sc;
#pragma unroll
            for (int ll = 0; ll < 16; ++ll) {
                const int l = half * 16 + ll;
                const float wl = sm.attn.w_s[l];
                float2 f2 = __half22float2(*reinterpret_cast<const __half2*>(&sm.attn.enc[l * 261 + col]));
                vx += wl * f2.x; vy += wl * f2.y;
            }
        }
        __syncthreads();
    }
    if (half == 1) { sm.attn.u_s[2 * col] = vx; sm.attn.u_s[2 * col + 1] = vy; }
    __syncthreads();
    if (half == 0) {
        vx += sm.attn.u_s[2 * col];
        vy += sm.attn.u_s[2 * col + 1];
        const int pc = b * NCH + ch;
        pv[(size_t)pc * HID + 2 * col]     = vx;
        pv[(size_t)pc * HID + 2 * col + 1] = vy;
        if (t == 0) { pm[pc] = sm.attn.msh[0]; ps[pc] = sm.attn.msh[1]; }
    }
}

// f32 fallback (direct global reads, no staging) — correctness path only
__device__ __forceinline__ void phase_attn32(SMem& sm, int bid,
    const float* __restrict__ uvec, const float* __restrict__ encf,
    float* __restrict__ pm, float* __restrict__ ps, float* __restrict__ pv)
{
    const int t    = threadIdx.x;
    const int b    = bid >> 2;
    const int ch   = bid & 3;
    const int half = t >> 8;
    const int col  = t & 255;
    const int le   = t & 31;
    const int seg  = t >> 5;
    sm.attn.u_s[t] = uvec[b * HID + t];
    if (t == 0) { sm.attn.msh[0] = -3.0e38f; sm.attn.msh[1] = 0.f; sm.attn.msh[2] = 0.f; }
    float vx = 0.f, vy = 0.f;
    __syncthreads();
    for (int blk = 0; blk < 8; ++blk) {
        const int l0 = ch * 256 + blk * 32;
        {
            const float* er = encf + ((size_t)b * LLEN + l0 + le) * HID + seg * 32;
            const float* us = sm.attn.u_s + seg * 32;
            float eacc = 0.f;
#pragma unroll
            for (int k = 0; k < 32; ++k) eacc += er[k] * us[k];
            sm.attn.accs[seg][le] = eacc;
        }
        __syncthreads();
        if (t < 32) {
            float e = 0.f;
#pragma unroll
            for (int s2 = 0; s2 < 16; ++s2) e += sm.attn.accs[s2][t];
            float bm = e;
#pragma unroll
            for (int off = 16; off > 0; off >>= 1) bm = fmaxf(bm, __shfl_xor(bm, off));
            const float m_old = sm.attn.msh[0];
            const float m_new = fmaxf(m_old, bm);
            const float wl = __expf(e - m_new);
            float sw = wl;
#pragma unroll
            for (int off = 16; off > 0; off >>= 1) sw += __shfl_xor(sw, off);
            sm.attn.w_s[t] = wl;
            if (t == 0) {
                const float sc = __expf(m_old - m_new);
                sm.attn.msh[2] = sc;
                sm.attn.msh[1] = sm.attn.msh[1] * sc + sw;
                sm.attn.msh[0] = m_new;
            }
        }
        __syncthreads();
        {
            const float sc = sm.attn.msh[2];
            vx *= sc; vy *= sc;
#pragma unroll
            for (int ll = 0; ll < 16; ++ll) {
                const int l = half * 16 + ll;
                const float wl = sm.attn.w_s[l];
                float2 f2 = *reinterpret_cast<const float2*>(encf + ((size_t)b * LLEN + l0 + l) * HID + 2 * col);
                vx += wl * f2.x; vy += wl * f2.y;
            }
        }
        __syncthreads();
    }
    if (half == 1) { sm.attn.u_s[2 * col] = vx; sm.attn.u_s[2 * col + 1] = vy; }
    __syncthreads();
    if (half == 0) {
        vx += sm.attn.u_s[2 * col];
        vy += sm.attn.u_s[2 * col + 1];
        const int pc = b * NCH + ch;
        pv[(size_t)pc * HID + 2 * col]     = vx;
        pv[(size_t)pc * HID + 2 * col + 1] = vy;
        if (t == 0) { pm[pc] = sm.attn.msh[0]; ps[pc] = sm.attn.msh[1]; }
    }
}

// ---------------------------------------------------------------------------
template<int USE16>
__global__ __launch_bounds__(NT, 1)
void k_seq(const float* __restrict__ xemb, const __half* __restrict__ enc16,
           const float* __restrict__ encf,
           const float* __restrict__ aWih, const float* __restrict__ aWhh,
           const float* __restrict__ abih, const float* __restrict__ abhh,
           const float* __restrict__ rWih, const float* __restrict__ rWhh,
           const float* __restrict__ rbih, const float* __restrict__ rbhh,
           const float* __restrict__ Pm, const float* __restrict__ p0v,
           const float* __restrict__ Whw, const float* __restrict__ Whb,
           const float* __restrict__ W1, const float* __restrict__ b1,
           const float* __restrict__ W2, const float* __restrict__ b2,
           float* h0, float* c0, float* hs, float* cs,
           float* ctxb, float* ub, float* chat, float* hpart, float* hid,
           float* pm, float* ps, float* pv, float* out, unsigned* bar)
{
    __shared__ SMem sm;
    const int bid = blockIdx.x;
    const int i0  = bid * 2;
    unsigned nb = 0;

    for (int t = 0; t < SLEN; ++t) {
        const int par = t & 1;
        float* h0r = h0 + par * BS * HID;
        float* h0w = h0 + (par ^ 1) * BS * HID;
        float* hsr = hs + par * NL * BS * HID;
        float* hsw = hs + (par ^ 1) * NL * BS * HID;
        float* prev = hsw + BS * HID;

        // A: finish hid(t-1), then attention-input LSTM cell
        if (t > 0) phase_H(sm, i0, ctxb, W1, hpart, hid);
        phase_cell<EMB, true>(sm, i0, xemb + (size_t)t * BS * EMB, ctxb, h0r,
                              aWih, EMB + HID, aWhh, abih, abhh, c0, h0w);
        gridbar(bar, ++nb);
        // B: rnn layer 0
        phase_cell<HID, false>(sm, i0, h0w, nullptr, hsr,
                               rWih, HID, rWhh, rbih, rbhh, cs, hsw);
        gridbar(bar, ++nb);
        // C: rnn layer 1
        phase_cell<HID, false>(sm, i0, hsw, nullptr, hsr + BS * HID,
                               rWih + (size_t)G4 * HID, HID, rWhh + (size_t)G4 * HID,
                               rbih + G4, rbhh + G4, cs + BS * HID, prev);
        gridbar(bar, ++nb);
        // D: logits(t-1) + dual GEMV (u, hpart)
        if (t > 0) phase_logits(sm, bid, hid, W2, b2, out, t - 1);
        phase_dual(sm, i0, prev, Pm, p0v, ub, W1, b1, hpart);
        gridbar(bar, ++nb);
        // E: attention partials
        if constexpr (USE16) phase_attn16(sm, bid, ub, enc16, pm, ps, pv);
        else                 phase_attn32(sm, bid, ub, encf, pm, ps, pv);
        gridbar(bar, ++nb);
        // F: combine -> chat
        phase_F(bid, pm, ps, pv, chat);
        gridbar(bar, ++nb);
        // G: ctx = Whw@chat + Whb
        phase_G(sm, i0, chat, Whw, Whb, ctxb);
        gridbar(bar, ++nb);
    }
    phase_H(sm, i0, ctxb, W1, hpart, hid);
    gridbar(bar, ++nb);
    phase_logits(sm, bid, hid, W2, b2, out, SLEN - 1);
}

// ---------------------------------------------------------------------------
extern "C" void kernel_launch(void* const* d_in, const int* in_sizes, int n_in,
                              void* d_out, int out_size, void* d_ws, size_t ws_size,
                              hipStream_t stream)
{
    const int*   y    = (const int*)  d_in[0];
    const float* enc  = (const float*)d_in[1];
    const float* emb  = (const float*)d_in[2];
    const float* aWih = (const float*)d_in[3];
    const float* aWhh = (const float*)d_in[4];
    const float* abih = (const float*)d_in[5];
    const float* abhh = (const float*)d_in[6];
    const float* rWih = (const float*)d_in[7];
    const float* rWhh = (const float*)d_in[8];
    const float* rbih = (const float*)d_in[9];
    const float* rbhh = (const float*)d_in[10];
    const float* Wsw  = (const float*)d_in[11];
    const float* Wsb  = (const float*)d_in[12];
    const float* Whw  = (const float*)d_in[13];
    const float* Whb  = (const float*)d_in[14];
    const float* W1   = (const float*)d_in[15];
    const float* b1   = (const float*)d_in[16];
    const float* W2   = (const float*)d_in[17];
    const float* b2   = (const float*)d_in[18];
    float* out = (float*)d_out;

    unsigned* bar = (unsigned*)d_ws;
    float* p = (float*)((char*)d_ws + 1024);
    // zeroed-region (contiguous): h0(2), c0, hs(2), cs, ctxb
    float* h0   = p;  p += 2 * BS * HID;
    float* c0   = p;  p += BS * HID;
    float* hs   = p;  p += 2 * NL * BS * HID;
    float* cs   = p;  p += NL * BS * HID;
    float* ctxb = p;  p += BS * HID;
    // live buffers
    float* ub    = p;  p += BS * HID;
    float* chat  = p;  p += BS * HID;
    float* hpart = p;  p += BS * HID;
    float* hid   = p;  p += BS * HID;
    float* Pm    = p;  p += HID * HID;
    float* p0v   = p;  p += HID;
    float* pmb   = p;  p += BS * NCH;
    float* psb   = p;  p += BS * NCH;
    float* pvb   = p;  p += (size_t)BS * NCH * HID;
    float* xemb  = p;  p += (size_t)SLEN * BS * EMB;
    __half* enc16 = (__half*)p;
    size_t need = (size_t)((char*)p - (char*)d_ws) + sizeof(__half) * (size_t)BS * LLEN * HID;
    const bool use16 = (ws_size >= need);

    hipMemsetAsync(bar, 0, 1024, stream);
    size_t zeroFloats = (size_t)(2 + 1 + 2 * NL + NL + 1) * BS * HID;
    hipMemsetAsync(h0, 0, zeroFloats * sizeof(float), stream);

    k_embed<<<(SLEN * BS * EMB) / 256, 256, 0, stream>>>(y, emb, xemb);
    if (use16) k_cast<<<4096, 256, 0, stream>>>(enc, enc16, (BS * LLEN * HID) / 4);
    k_pmat<<<HID, 256, 0, stream>>>(Whw, Wsw, Wsb, Pm, p0v);

    if (use16)
        k_seq<1><<<NB, NT, 0, stream>>>(xemb, enc16, nullptr,
            aWih, aWhh, abih, abhh, rWih, rWhh, rbih, rbhh,
            Pm, p0v, Whw, Whb, W1, b1, W2, b2,
            h0, c0, hs, cs, ctxb, ub, chat, hpart, hid,
            pmb, psb, pvb, out, bar);
    else
        k_seq<0><<<NB, NT, 0, stream>>>(xemb, nullptr, enc,
            aWih, aWhh, abih, abhh, rWih, rWhh, rbih, rbhh,
            Pm, p0v, Whw, Whb, W1, b1, W2, b2,
            h0, c0, hs, cs, ctxb, ub, chat, hpart, hid,
            pmb, psb, pvb, out, bar);
}